// Round 18
// baseline (197.073 us; speedup 1.0000x reference)
//
#include <hip/hip_runtime.h>
#include <hip/hip_bf16.h>
#include <hip/hip_fp16.h>
#include <math.h>

#define N_NODES 50000
#define N_EDGES 800000
#define DIM 128
#define NHEAD 8
#define DHEAD 16
#define SDIM 10
#define NSCAN_BLK 196   // ceil(N_NODES/256)
#define SETUP_W 48      // weight-prep blocks (6 matrices x 8 slices)
#define SETUP_CNT 3125  // count_deg blocks
#define SETUP_SEC 1563  // secbias blocks
#define HQKV_GRID 391   // (N_NODES+127)/128; also covers fill: 391*512*4 >= E

typedef __attribute__((ext_vector_type(8))) short bf16x8;
typedef __attribute__((ext_vector_type(4))) float f32x4;
typedef float f32x2 __attribute__((ext_vector_type(2)));

#if __has_builtin(__builtin_amdgcn_cvt_pk_f32_fp8)
#define HAVE_FP8_DEC 1
#else
#define HAVE_FP8_DEC 0
#endif
#if __has_builtin(__builtin_amdgcn_cvt_pk_fp8_f32)
#define HAVE_FP8_ENC 1
#else
#define HAVE_FP8_ENC 0
#endif

__device__ __forceinline__ float bf2f(unsigned short u) {
    return __uint_as_float(((unsigned)u) << 16);
}
__device__ __forceinline__ unsigned short f2bf(float f) {
    unsigned u = __float_as_uint(f);
    return (unsigned short)((u + 0x7FFFu + ((u >> 16) & 1u)) >> 16);
}

// ---- fp8 e4m3fn helpers (HW cvt when available; exact manual fallback) ----
__device__ __forceinline__ float fp8dec1(unsigned b) {
    unsigned short hb = (unsigned short)(((b & 0x80u) << 8) | ((b & 0x7Fu) << 7));
    __half hh = *reinterpret_cast<__half*>(&hb);
    return __half2float(hh) * 256.f;
}
template <bool HI>
__device__ __forceinline__ f32x2 dec2fp8(unsigned w) {
#if HAVE_FP8_DEC
    return __builtin_amdgcn_cvt_pk_f32_fp8((int)w, HI);
#else
    unsigned b0 = HI ? ((w >> 16) & 0xFFu) : (w & 0xFFu);
    unsigned b1 = HI ? (w >> 24) : ((w >> 8) & 0xFFu);
    f32x2 r; r.x = fp8dec1(b0); r.y = fp8dec1(b1); return r;
#endif
}
__device__ __forceinline__ unsigned char f2fp8(float f) {
#if HAVE_FP8_ENC
    return (unsigned char)(__builtin_amdgcn_cvt_pk_fp8_f32(f, f, 0, false) & 0xFF);
#else
    unsigned u = __float_as_uint(f);
    unsigned s = (u >> 24) & 0x80u;
    float a = fabsf(f);
    if (a >= 464.f) return (unsigned char)(s | 0x7E);     // clamp to 448
    if (a < 0.015625f) {                                  // subnormal: q/512
        int q = (int)rintf(a * 512.f);
        return (unsigned char)(s | (unsigned)q);
    }
    int e = (int)((u >> 23) & 0xFF) - 127;
    unsigned man = u & 0x7FFFFFu;
    unsigned keep = man >> 20, rest = man & 0xFFFFFu;
    if (rest > 0x80000u || (rest == 0x80000u && (keep & 1u))) {
        if (++keep == 8u) { keep = 0u; ++e; if (e > 8) return (unsigned char)(s | 0x7E); }
    }
    return (unsigned char)(s | ((unsigned)(e + 7) << 3) | keep);
#endif
}

// ===== setup: weight prep (48 blks) + count_deg (3125 blks) + secbias =======
__global__ __launch_bounds__(256) void setup_kernel(
    const float* __restrict__ W1, const float* __restrict__ Wq,
    const float* __restrict__ Wk, const float* __restrict__ Wv,
    const float* __restrict__ Wo, const float* __restrict__ W2,
    unsigned short* __restrict__ Wt, const int* __restrict__ dst,
    int* __restrict__ deg, const float* __restrict__ sec,
    const float* __restrict__ Wsec, const float* __restrict__ bsec,
    float* __restrict__ secb) {
    const int b = blockIdx.x, t = threadIdx.x;
    if (b < SETUP_W) {
        const int mtx = b >> 3, slice = b & 7;
        const float* W = (mtx == 0) ? W1 : (mtx == 1) ? Wq : (mtx == 2) ? Wk :
                         (mtx == 3) ? Wv : (mtx == 4) ? Wo : W2;
        unsigned short* o = Wt + mtx * 16384;
#pragma unroll
        for (int i = 0; i < 8; ++i) {
            int idx = slice * 2048 + t + 256 * i;   // k-major element index
            int k = idx >> 7, n = idx & 127;
            o[n * 128 + k] = f2bf(W[idx]);
        }
    } else if (b < SETUP_W + SETUP_CNT) {           // count_deg
        int e = (b - SETUP_W) * 256 + t;
        if (e < N_EDGES) atomicAdd(&deg[dst[e]], 1);
    } else {                                        // secbias
        int idx = (b - SETUP_W - SETUP_CNT) * 256 + t;
        if (idx < N_NODES * NHEAD) {
            int n = idx >> 3, h = idx & 7;
            float acc = bsec[h];
#pragma unroll
            for (int j = 0; j < SDIM; ++j)
                acc = fmaf(sec[n * SDIM + j], Wsec[j * NHEAD + h], acc);
            secb[idx] = acc;
        }
    }
}

__global__ __launch_bounds__(256) void blocksum_kernel(const int* __restrict__ deg,
                                                       int* __restrict__ bsum) {
    const int t = threadIdx.x;
    int idx = blockIdx.x * 256 + t;
    int v = (idx < N_NODES) ? deg[idx] : 0;
#pragma unroll
    for (int m = 32; m; m >>= 1) v += __shfl_xor(v, m);
    __shared__ int ws[4];
    if ((t & 63) == 0) ws[t >> 6] = v;
    __syncthreads();
    if (t == 0) bsum[blockIdx.x] = ws[0] + ws[1] + ws[2] + ws[3];
}

__global__ __launch_bounds__(256) void scanfin2_kernel(const int* __restrict__ deg,
                                                       const int* __restrict__ bsum,
                                                       int* __restrict__ rowstart) {
    const int t = threadIdx.x, b = blockIdx.x;
    int v0 = (t < b) ? bsum[t] : 0;
#pragma unroll
    for (int m = 32; m; m >>= 1) v0 += __shfl_xor(v0, m);
    __shared__ int ws[4];
    if ((t & 63) == 0) ws[t >> 6] = v0;
    __syncthreads();
    const int bexc = ws[0] + ws[1] + ws[2] + ws[3];

    int idx = b * 256 + t;
    int v = (idx < N_NODES) ? deg[idx] : 0;
    __shared__ int s[256];
    __syncthreads();
    s[t] = v;
    __syncthreads();
#pragma unroll
    for (int off = 1; off < 256; off <<= 1) {
        int x = (t >= off) ? s[t - off] : 0;
        __syncthreads();
        s[t] += x;
        __syncthreads();
    }
    if (idx < N_NODES) rowstart[idx] = bexc + s[t] - v;
    if (b == 0 && t == 0) rowstart[N_NODES] = N_EDGES;
}

// ===== fused: EVERY block = fill prologue (4 edges/thread) + h+q/k/v GEMM ==
// Fill's latency chains (atomics + scattered stores) are issued before the
// first barrier and hide under the GEMM's staging/MFMA phases via wave
// co-scheduling — no fill-only blocks idling CUs.
// q,v,h stored bf16; k stored fp8 e4m3.
__global__ __launch_bounds__(512) void fill_hqkv_kernel(
    const int* __restrict__ src, const int* __restrict__ dst,
    const int* __restrict__ rowstart, int* __restrict__ ctr,
    int2* __restrict__ epair,
    const float* __restrict__ X, const unsigned short* __restrict__ Wt,
    const float* __restrict__ b1, const float* __restrict__ bq,
    const float* __restrict__ bk, const float* __restrict__ bv,
    unsigned short* __restrict__ hb, unsigned short* __restrict__ qo,
    unsigned char* __restrict__ ko8, unsigned short* __restrict__ vo, int nrows) {
    __shared__ alignas(16) unsigned char Wl[32768];
    __shared__ alignas(16) unsigned char Ht[32768];   // 8 waves x 16 rows x 256B
    const int t = threadIdx.x;

    // ------------- fill prologue: 4 edges/thread, batched chains -------------
    {
        int base = blockIdx.x * 2048 + t;
        int dd[4], sr[4]; bool ok[4];
#pragma unroll
        for (int i = 0; i < 4; ++i) {
            int e = base + i * 512;
            ok[i] = e < N_EDGES;
            dd[i] = ok[i] ? dst[e] : 0;
            sr[i] = ok[i] ? src[e] : 0;
        }
        int pos[4];
#pragma unroll
        for (int i = 0; i < 4; ++i)
            if (ok[i]) pos[i] = atomicAdd(&ctr[dd[i]], 1);
#pragma unroll
        for (int i = 0; i < 4; ++i)
            if (ok[i]) epair[rowstart[dd[i]] + pos[i]] = make_int2(sr[i], base + i * 512);
    }

    // ---------------- h + q/k/v GEMM ----------------
    const int l = t & 63, wave = t >> 6;
    const int l15 = l & 15, lg = l >> 4;
    const int r0 = blockIdx.x * 128 + wave * 16;
    const int arow = r0 + l15;
    const bool aok = arow < nrows;
    const int orow0 = r0 + lg * 4;
    unsigned char* HtW = Ht + wave * 4096;

    // stage W1
#pragma unroll
    for (int i = 0; i < 4; ++i) {
        int c = t + 512 * i;                 // 2048 16B chunks
        int n = c >> 4, s = c & 15;
        bf16x8 val = *(const bf16x8*)(Wt + c * 8);
        *(bf16x8*)(Wl + n * 256 + ((s * 16) ^ ((n & 7) << 4))) = val;
    }
    // x f32 -> bf16 A-frags
    bf16x8 af[4];
#pragma unroll
    for (int k0 = 0; k0 < 4; ++k0) {
        float4 a0 = {0.f, 0.f, 0.f, 0.f}, a1 = {0.f, 0.f, 0.f, 0.f};
        if (aok) {
            const float4* ap = (const float4*)(X + (size_t)arow * DIM + k0 * 32 + lg * 8);
            a0 = ap[0]; a1 = ap[1];
        }
        bf16x8 f;
        f[0] = (short)f2bf(a0.x); f[1] = (short)f2bf(a0.y);
        f[2] = (short)f2bf(a0.z); f[3] = (short)f2bf(a0.w);
        f[4] = (short)f2bf(a1.x); f[5] = (short)f2bf(a1.y);
        f[6] = (short)f2bf(a1.z); f[7] = (short)f2bf(a1.w);
        af[k0] = f;
    }
    __syncthreads();

    {
        f32x4 acc[8];
#pragma unroll
        for (int n = 0; n < 8; ++n) acc[n] = (f32x4){0.f, 0.f, 0.f, 0.f};
#pragma unroll
        for (int k0 = 0; k0 < 4; ++k0) {
#pragma unroll
            for (int n = 0; n < 8; ++n) {
                int row = n * 16 + l15;
                int kb = (k0 * 64 + lg * 16) ^ ((row & 7) << 4);
                bf16x8 bfr = *(bf16x8*)(Wl + row * 256 + kb);
                acc[n] = __builtin_amdgcn_mfma_f32_16x16x32_bf16(af[k0], bfr, acc[n], 0, 0, 0);
            }
        }
        // epilogue: h = relu(acc + b1) -> hb + per-wave Ht region
#pragma unroll
        for (int n = 0; n < 8; ++n) {
            int col = n * 16 + l15;
            float bvv = b1[col];
#pragma unroll
            for (int i = 0; i < 4; ++i) {
                int rloc = lg * 4 + i;
                unsigned short hv = f2bf(fmaxf(acc[n][i] + bvv, 0.f));
                if (orow0 + i < nrows) hb[(size_t)(orow0 + i) * DIM + col] = hv;
                *(unsigned short*)(HtW + ((rloc * 256 + col * 2) ^ ((rloc & 7) << 4))) = hv;
            }
        }
    }

    // A-frags of h from own wave's Ht region (intra-wave, LDS ops ordered)
    bf16x8 af2[4];
#pragma unroll
    for (int k0 = 0; k0 < 4; ++k0)
        af2[k0] = *(const bf16x8*)(HtW + ((l15 * 256 + k0 * 64 + lg * 16) ^ ((l15 & 7) << 4)));
    __syncthreads();

    for (int m = 0; m < 3; ++m) {
        const unsigned short* wsrc = (m == 0) ? Wt + 16384 : (m == 1) ? Wt + 32768 : Wt + 49152;
        const float* bias = (m == 0) ? bq : (m == 1) ? bk : bv;
#pragma unroll
        for (int i = 0; i < 4; ++i) {
            int c = t + 512 * i;
            int n = c >> 4, s = c & 15;
            bf16x8 val = *(const bf16x8*)(wsrc + c * 8);
            *(bf16x8*)(Wl + n * 256 + ((s * 16) ^ ((n & 7) << 4))) = val;
        }
        __syncthreads();
        f32x4 acc[8];
#pragma unroll
        for (int n = 0; n < 8; ++n) acc[n] = (f32x4){0.f, 0.f, 0.f, 0.f};
#pragma unroll
        for (int k0 = 0; k0 < 4; ++k0) {
#pragma unroll
            for (int n = 0; n < 8; ++n) {
                int row = n * 16 + l15;
                int kb = (k0 * 64 + lg * 16) ^ ((row & 7) << 4);
                bf16x8 bfr = *(bf16x8*)(Wl + row * 256 + kb);
                acc[n] = __builtin_amdgcn_mfma_f32_16x16x32_bf16(af2[k0], bfr, acc[n], 0, 0, 0);
            }
        }
#pragma unroll
        for (int n = 0; n < 8; ++n) {
            int col = n * 16 + l15;
            float bvv = bias[col];
#pragma unroll
            for (int i = 0; i < 4; ++i) {
                int r = orow0 + i;
                if (r < nrows) {
                    float val = acc[n][i] + bvv;
                    if (m == 0)      qo[(size_t)r * DIM + col] = f2bf(val);
                    else if (m == 1) ko8[(size_t)r * DIM + col] = f2fp8(val);
                    else             vo[(size_t)r * DIM + col] = f2bf(val);
                }
            }
        }
        __syncthreads();   // before next restage
    }
}

// fp8 k-row dot against qv[16] floats (row = 16B at kb8 + s*128 + h*16)
__device__ __forceinline__ float score_dot_fp8(const float* qv, uint4 kw) {
    float a0 = 0.f, a1 = 0.f;
    f32x2 p;
    p = dec2fp8<false>(kw.x); a0 = fmaf(qv[0],  p.x, a0); a1 = fmaf(qv[1],  p.y, a1);
    p = dec2fp8<true >(kw.x); a0 = fmaf(qv[2],  p.x, a0); a1 = fmaf(qv[3],  p.y, a1);
    p = dec2fp8<false>(kw.y); a0 = fmaf(qv[4],  p.x, a0); a1 = fmaf(qv[5],  p.y, a1);
    p = dec2fp8<true >(kw.y); a0 = fmaf(qv[6],  p.x, a0); a1 = fmaf(qv[7],  p.y, a1);
    p = dec2fp8<false>(kw.z); a0 = fmaf(qv[8],  p.x, a0); a1 = fmaf(qv[9],  p.y, a1);
    p = dec2fp8<true >(kw.z); a0 = fmaf(qv[10], p.x, a0); a1 = fmaf(qv[11], p.y, a1);
    p = dec2fp8<false>(kw.w); a0 = fmaf(qv[12], p.x, a0); a1 = fmaf(qv[13], p.y, a1);
    p = dec2fp8<true >(kw.w); a0 = fmaf(qv[14], p.x, a0); a1 = fmaf(qv[15], p.y, a1);
    return a0 + a1;
}

// ===== fused scores + softmax + aggregation (wave per dst node) ============
__global__ __launch_bounds__(256) void node_attn_kernel(
    const unsigned short* __restrict__ qb, const unsigned char* __restrict__ kb8,
    const unsigned short* __restrict__ vb, const float* __restrict__ secb,
    const int2* __restrict__ epair, const int* __restrict__ rowstart,
    float* __restrict__ attn_out, unsigned short* __restrict__ aggb) {
    int node = blockIdx.x * 4 + (threadIdx.x >> 6);
    if (node >= N_NODES) return;
    const int lane = threadIdx.x & 63;
    const int start = rowstart[node];
    const int deg = rowstart[node + 1] - start;
    if (deg == 0) {
        ((unsigned*)(aggb + (size_t)node * DIM))[lane] = 0u;
        return;
    }
    const int h = lane & 7;     // head (score phases)
    const int le = lane >> 3;   // edge slot 0..7
    const int hc = le;          // head (aggregation mapping)

    float qv[16];
    {
        const bf16x8* qp = (const bf16x8*)(qb + (size_t)node * DIM + h * DHEAD);
        bf16x8 q0 = qp[0], q1 = qp[1];
#pragma unroll
        for (int i = 0; i < 8; ++i) {
            qv[i] = bf2f((unsigned short)q0[i]);
            qv[8 + i] = bf2f((unsigned short)q1[i]);
        }
    }

    if (deg <= 64) {
        // ---------- fast path: coalesced int2 preload + register scores ----
        int sall = 0, eall = 0;
        if (lane < deg) {
            int2 p = epair[start + lane];
            sall = p.x;
            eall = p.y;
        }
        float sc[8];
        float m = -INFINITY;
#pragma unroll
        for (int t = 0; t < 8; ++t) {
            sc[t] = -INFINITY;
            if (t * 8 < deg) {                       // wave-uniform
                int jj = t * 8 + le;
                bool valid = jj < deg;
                int s = __shfl(sall, valid ? jj : deg - 1);
                uint4 kw = *(const uint4*)(kb8 + (size_t)s * DIM + h * 16);
                float acc = score_dot_fp8(qv, kw);
                if (valid) sc[t] = acc * 0.25f + secb[s * NHEAD + h];
            }
            m = fmaxf(m, sc[t]);
        }
        m = fmaxf(m, __shfl_xor(m, 8));
        m = fmaxf(m, __shfl_xor(m, 16));
        m = fmaxf(m, __shfl_xor(m, 32));

        float ev[8];
        float ssum = 0.f;
#pragma unroll
        for (int t = 0; t < 8; ++t) {
            ev[t] = (t * 8 + le < deg) ? __expf(sc[t] - m) : 0.f;
            ssum += ev[t];
        }
        ssum += __shfl_xor(ssum, 8);
        ssum += __shfl_xor(ssum, 16);
        ssum += __shfl_xor(ssum, 32);
        const float rinv = 1.f / (ssum + 1e-9f);     // head (lane&7)

        float2 acc2 = {0.f, 0.f};
#pragma unroll
        for (int t = 0; t < 8; ++t) {
            if (t * 8 < deg) {                       // wave-uniform
                // batch all 8 gathers (independent, in flight together)
                unsigned vvr[8];
#pragma unroll
                for (int le2 = 0; le2 < 8; ++le2) {
                    int jj = t * 8 + le2;            // uniform
                    int s = __shfl(sall, (jj < deg) ? jj : deg - 1);  // uniform
                    vvr[le2] = ((const unsigned*)(vb + (size_t)s * DIM))[lane];
                }
#pragma unroll
                for (int le2 = 0; le2 < 8; ++le2) {
                    float evd = __shfl(ev[t], le2 * 8 + hc);
                    acc2.x = fmaf(evd, bf2f((unsigned short)(vvr[le2] & 0xFFFFu)), acc2.x);
                    acc2.y = fmaf(evd, bf2f((unsigned short)(vvr[le2] >> 16)), acc2.y);
                }
            }
        }
        const float rinv_c = __shfl(rinv, hc);       // head (lane>>3)
        unsigned short o0 = f2bf(acc2.x * rinv_c);
        unsigned short o1 = f2bf(acc2.y * rinv_c);
        ((unsigned*)(aggb + (size_t)node * DIM))[lane] =
            (unsigned)o0 | ((unsigned)o1 << 16);

        // attn write: shfl hoisted OUT of the divergent guard (EXEC-safe)
#pragma unroll
        for (int t = 0; t < 8; ++t) {
            int jj = t * 8 + le;
            int e = __shfl(eall, (jj < deg) ? jj : 0);   // all lanes execute
            if (jj < deg) attn_out[(size_t)e * NHEAD + h] = ev[t] * rinv;
        }
        return;
    }

    // ---------- slow path (deg > 64): memory-staged, always correct ----------
    float m = -INFINITY;
    for (int j = 0; j < deg; j += 8) {
        int jj = j + le;
        float sc = -INFINITY;
        if (jj < deg) {
            int2 p = epair[start + jj];
            int s = p.x;
            uint4 kw = *(const uint4*)(kb8 + (size_t)s * DIM + h * 16);
            float acc = score_dot_fp8(qv, kw);
            sc = acc * 0.25f + secb[s * NHEAD + h];
            attn_out[(size_t)p.y * NHEAD + h] = sc;
        }
        m = fmaxf(m, sc);
    }
    m = fmaxf(m, __shfl_xor(m, 8));
    m = fmaxf(m, __shfl_xor(m, 16));
    m = fmaxf(m, __shfl_xor(m, 32));

    float ssum = 0.f;
    float2 acc2 = {0.f, 0.f};
    for (int j = 0; j < deg; j += 8) {
        int jj = j + le;
        float ev = 0.f;
        if (jj < deg) {
            int e = epair[start + jj].y;
            ev = __expf(attn_out[(size_t)e * NHEAD + h] - m);
        }
        ssum += ev;
        int lim = deg - j; if (lim > 8) lim = 8;
        for (int le2 = 0; le2 < lim; ++le2) {
            float evd = __shfl(ev, le2 * 8 + hc);
            int s = epair[start + j + le2].x;
            unsigned vv = ((const unsigned*)(vb + (size_t)s * DIM))[lane];
            acc2.x = fmaf(evd, bf2f((unsigned short)(vv & 0xFFFFu)), acc2.x);
            acc2.y = fmaf(evd, bf2f((unsigned short)(vv >> 16)), acc2.y);
        }
    }
    ssum += __shfl_xor(ssum, 8);
    ssum += __shfl_xor(ssum, 16);
    ssum += __shfl_xor(ssum, 32);
    const float rinv = 1.f / (ssum + 1e-9f);
    const float rinv_c = __shfl(rinv, hc);

    unsigned short o0 = f2bf(acc2.x * rinv_c);
    unsigned short o1 = f2bf(acc2.y * rinv_c);
    ((unsigned*)(aggb + (size_t)node * DIM))[lane] =
        (unsigned)o0 | ((unsigned)o1 << 16);

    for (int j = 0; j < deg; j += 8) {
        int jj = j + le;
        if (jj < deg) {
            int e = epair[start + jj].y;
            float sc = attn_out[(size_t)e * NHEAD + h];
            attn_out[(size_t)e * NHEAD + h] = __expf(sc - m) * rinv;
        }
    }
}

// ===== fused double GEMM+LN: out = LN2(mid + relu(mid@W2+b2)),
//       mid = LN1(hb + agg@Wo+bo); round-11 form: Wl+Mt LDS, barriers.
__global__ __launch_bounds__(512) void gemm_ln12_kernel(
    const unsigned short* __restrict__ A,      // aggb
    const unsigned short* __restrict__ Wt,     // Wo @ +0, W2 @ +16384
    const float* __restrict__ bo, const float* __restrict__ b2,
    const unsigned short* __restrict__ resid,  // hb
    const float* __restrict__ g1, const float* __restrict__ be1,
    const float* __restrict__ g2, const float* __restrict__ be2,
    float* __restrict__ outp, int nrows) {
    __shared__ alignas(16) unsigned char Wl[32768];
    __shared__ alignas(16) unsigned char Mt[32768];
    const int t = threadIdx.x;
    const int l = t & 63, wave = t >> 6;
    const int l15 = l & 15, lg = l >> 4;
    const int r0 = blockIdx.x * 128 + wave * 16;
    const int arow = r0 + l15;
    const bool aok = arow < nrows;
    const int orow0 = r0 + lg * 4;
    unsigned char* MtW = Mt + wave * 4096;

    // stage Wo
#pragma unroll
    for (int i = 0; i < 4; ++i) {
        int c = t + 512 * i;
        int n = c >> 4, s = c & 15;
        bf16x8 val = *(const bf16x8*)(Wt + c * 8);
        *(bf16x8*)(Wl + n * 256 + ((s * 16) ^ ((n & 7) << 4))) = val;
    }
    bf16x8 af[4];
#pragma unroll
    for (int k0 = 0; k0 < 4; ++k0) {
        bf16x8 z = (bf16x8){0, 0, 0, 0, 0, 0, 0, 0};
        af[k0] = aok ? *(const bf16x8*)(A + (size_t)arow * DIM + k0 * 32 + lg * 8) : z;
    }
    __syncthreads();

    float mid[8][4];    // bf16-rounded mid values, kept for LN2 residual
    {
        f32x4 acc[8];
#pragma unroll
        for (int n = 0; n < 8; ++n) acc[n] = (f32x4){0.f, 0.f, 0.f, 0.f};
#pragma unroll
        for (int k0 = 0; k0 < 4; ++k0) {
#pragma unroll
            for (int n = 0; n < 8; ++n) {
                int row = n * 16 + l15;
                int kb = (k0 * 64 + lg * 16) ^ ((row & 7) << 4);
                bf16x8 bfr = *(bf16x8*)(Wl + row * 256 + kb);
                acc[n] = __builtin_amdgcn_mfma_f32_16x16x32_bf16(af[k0], bfr, acc[n], 0, 0, 0);
            }
        }
        float bv[8], gv[8], bev[8];
#pragma unroll
        for (int n = 0; n < 8; ++n) {
            int col = n * 16 + l15;
            bv[n] = bo[col]; gv[n] = g1[col]; bev[n] = be1[col];
        }
#pragma unroll
        for (int i = 0; i < 4; ++i) {
            int r = orow0 + i;
            int rloc = lg * 4 + i;
            float xv[8];
            float s = 0.f;
            if (r < nrows) {
#pragma unroll
                for (int n = 0; n < 8; ++n) {
                    float val = acc[n][i] + bv[n]
                              + bf2f(resid[(size_t)r * DIM + n * 16 + l15]);
                    xv[n] = val;
                    s += val;
                }
            } else {
#pragma unroll
                for (int n = 0; n < 8; ++n) xv[n] = 0.f;
            }
            s += __shfl_xor(s, 1); s += __shfl_xor(s, 2);
            s += __shfl_xor(s, 4); s += __shfl_xor(s, 8);
            float mean = s * (1.f / 128.f);
            float var = 0.f;
#pragma unroll
            for (int n = 0; n < 8; ++n) {
                float d = xv[n] - mean;
                var += d * d;
            }
            var += __shfl_xor(var, 1); var += __shfl_xor(var, 2);
            var += __shfl_xor(var, 4); var += __shfl_xor(var, 8);
            float rstd = rsqrtf(var * (1.f / 128.f) + 1e-5f);
#pragma unroll
            for (int n = 0; n < 8; ++n) {
                int col = n * 16 + l15;
                unsigned short mb = f2bf((xv[n] - mean) * rstd * gv[n] + bev[n]);
                mid[n][i] = bf2f(mb);
                *(unsigned short*)(MtW + ((rloc * 256 + col * 2) ^ ((rloc & 7) << 4))) = mb;
            }
        }
    }
    __syncthreads();   // Wo reads + Mt writes complete

    bf16x8 af2[4];
#pragma unroll
    for (int k0 = 0; k0 < 4; ++k0)
        af2[k0] = *(const bf16x8*)(MtW + ((l15 * 256 + k0 * 64 + lg * 16) ^ ((l15 & 7) << 4)));

    // stage W2
#pragma unroll
    for (int i = 0; i < 4; ++i) {
        int c = t + 512 * i;
        int n = c >> 4, s = c & 15;
        bf16x8 val = *(const bf16x8*)(Wt + 16384 + c * 8);
        *(bf16x8*)(Wl + n * 256 + ((s * 16) ^ ((n & 7) << 4))) = val;
    }
    __syncthreads();

    {
        f32x4 acc[8];
#pragma unroll
        for (int n = 0; n < 8; ++n) acc[n] = (f32x4){0.f, 0.f, 0.f, 0.f};
#pragma unroll
        for (int k0 = 0; k0 < 4; ++k0) {
#pragma unroll
            for (int n = 0; n < 8; ++n) {
                int row = n * 16 + l15;
                int kb = (k0 * 64 + lg * 16) ^ ((row & 7) << 4);
                bf16x8 bfr = *(bf16x8*)(Wl + row * 256 + kb);
                acc[n] = __builtin_amdgcn_mfma_f32_16x16x32_bf16(af2[k0], bfr, acc[n], 0, 0, 0);
            }
        }
        float bv[8], gv[8], bev[8];
#pragma unroll
        for (int n = 0; n < 8; ++n) {
            int col = n * 16 + l15;
            bv[n] = b2[col]; gv[n] = g2[col]; bev[n] = be2[col];
        }
#pragma unroll
        for (int i = 0; i < 4; ++i) {
            int r = orow0 + i;
            float xv[8];
            float s = 0.f;
#pragma unroll
            for (int n = 0; n < 8; ++n) {
                float val = fmaxf(acc[n][i] + bv[n], 0.f) + mid[n][i];
                xv[n] = val;
                s += val;
            }
            s += __shfl_xor(s, 1); s += __shfl_xor(s, 2);
            s += __shfl_xor(s, 4); s += __shfl_xor(s, 8);
            float mean = s * (1.f / 128.f);
            float var = 0.f;
#pragma unroll
            for (int n = 0; n < 8; ++n) {
                float d = xv[n] - mean;
                var += d * d;
            }
            var += __shfl_xor(var, 1); var += __shfl_xor(var, 2);
            var += __shfl_xor(var, 4); var += __shfl_xor(var, 8);
            float rstd = rsqrtf(var * (1.f / 128.f) + 1e-5f);
            if (r < nrows) {
#pragma unroll
                for (int n = 0; n < 8; ++n) {
                    int col = n * 16 + l15;
                    outp[(size_t)r * DIM + col] = (xv[n] - mean) * rstd * gv[n] + bev[n];
                }
            }
        }
    }
}

extern "C" void kernel_launch(void* const* d_in, const int* in_sizes, int n_in,
                              void* d_out, int out_size, void* d_ws, size_t ws_size,
                              hipStream_t stream) {
    const float* x    = (const float*)d_in[0];
    const int*   ei   = (const int*)d_in[1];
    const float* sec  = (const float*)d_in[2];
    const float* W1   = (const float*)d_in[3];
    const float* b1   = (const float*)d_in[4];
    const float* W2   = (const float*)d_in[5];
    const float* b2   = (const float*)d_in[6];
    const float* Wq   = (const float*)d_in[7];
    const float* bq   = (const float*)d_in[8];
    const float* Wk   = (const float*)d_in[9];
    const float* bk   = (const float*)d_in[10];
    const float* Wv   = (const float*)d_in[11];
    const float* bvp  = (const float*)d_in[12];
    const float* Wsec = (const float*)d_in[13];
    const float* bsec = (const float*)d_in[14];
    const float* Wo   = (const float*)d_in[15];
    const float* bo   = (const float*)d_in[16];
    const float* g1   = (const float*)d_in[17];
    const float* be1  = (const float*)d_in[18];
    const float* g2   = (const float*)d_in[19];
    const float* be2  = (const float*)d_in[20];

    const int* srcp = ei;             // edge_index[0]
    const int* dstp = ei + N_EDGES;   // edge_index[1]

    char* wsb = (char*)d_ws;
    unsigned short* hb   = (unsigned short*)(wsb);              // 12.8MB bf16
    unsigned short* qbu  = (unsigned short*)(wsb + 12800000);   // bf16
    unsigned char*  kb8  = (unsigned char*)(wsb + 25600000);    // fp8, 6.4MB
    unsigned short* vbu  = (unsigned short*)(wsb + 38400000);   // bf16
    unsigned short* aggb = (unsigned short*)(wsb + 51200000);
    float* secb          = (float*)(wsb + 76800000);            // 1.6MB
    unsigned short* Wt   = (unsigned short*)(wsb + 78400000);   // 192KB
    int* deg             = (int*)(wsb + 78600000);              // 200KB
    int* ctr             = (int*)(wsb + 78800000);              // 200KB
    int* rowstart        = (int*)(wsb + 79000000);              // 200KB+4
    int2* epair          = (int2*)(wsb + 79200256);             // 6.4MB
    int* bsum            = (int*)(wsb + 85600512);              // 784B

    float* outp = (float*)d_out;                 // [N,128]
    float* attn = outp + (size_t)N_NODES * DIM;  // [E,8]

    dim3 blk(256);
    const int wgrid = (N_NODES + 3) / 4;             // 12500

    // zero deg+ctr (adjacent 400KB) — graph-capturable async memset
    hipMemsetAsync(deg, 0, 400000, stream);

    setup_kernel<<<SETUP_W + SETUP_CNT + SETUP_SEC, blk, 0, stream>>>(
        W1, Wq, Wk, Wv, Wo, W2, Wt, dstp, deg, sec, Wsec, bsec, secb);
    blocksum_kernel<<<NSCAN_BLK, blk, 0, stream>>>(deg, bsum);
    scanfin2_kernel<<<NSCAN_BLK, blk, 0, stream>>>(deg, bsum, rowstart);

    fill_hqkv_kernel<<<HQKV_GRID, dim3(512), 0, stream>>>(
        srcp, dstp, rowstart, ctr, epair,
        x, Wt, b1, bq, bk, bvp, hb, qbu, kb8, vbu, N_NODES);

    node_attn_kernel<<<wgrid, blk, 0, stream>>>(qbu, kb8, vbu, secb, epair,
                                                rowstart, attn, aggb);

    gemm_ln12_kernel<<<HQKV_GRID, dim3(512), 0, stream>>>(aggb, Wt + 65536, bo, b2, hb,
                                                          g1, be1, g2, be2, outp, N_NODES);
}

// Round 19
// 181.533 us; speedup vs baseline: 1.0856x; 1.0856x over previous
//
#include <hip/hip_runtime.h>
#include <hip/hip_bf16.h>
#include <hip/hip_fp16.h>
#include <math.h>

#define N_NODES 50000
#define N_EDGES 800000
#define DIM 128
#define NHEAD 8
#define DHEAD 16
#define SDIM 10
#define NSCAN_BLK 196   // ceil(N_NODES/256)
#define SETUP_W 48      // weight-prep blocks (6 matrices x 8 slices)
#define SETUP_CNT 3125  // count_deg blocks
#define SETUP_SEC 1563  // secbias blocks
#define HQKV_GRID 391   // (N_NODES+127)/128
#define FILL_GRID 1563  // ceil(N_EDGES/512)

typedef __attribute__((ext_vector_type(8))) short bf16x8;
typedef __attribute__((ext_vector_type(4))) float f32x4;
typedef float f32x2 __attribute__((ext_vector_type(2)));

#if __has_builtin(__builtin_amdgcn_cvt_pk_f32_fp8)
#define HAVE_FP8_DEC 1
#else
#define HAVE_FP8_DEC 0
#endif
#if __has_builtin(__builtin_amdgcn_cvt_pk_fp8_f32)
#define HAVE_FP8_ENC 1
#else
#define HAVE_FP8_ENC 0
#endif

__device__ __forceinline__ float bf2f(unsigned short u) {
    return __uint_as_float(((unsigned)u) << 16);
}
__device__ __forceinline__ unsigned short f2bf(float f) {
    unsigned u = __float_as_uint(f);
    return (unsigned short)((u + 0x7FFFu + ((u >> 16) & 1u)) >> 16);
}

// ---- fp8 e4m3fn helpers (HW cvt when available; exact manual fallback) ----
__device__ __forceinline__ float fp8dec1(unsigned b) {
    unsigned short hb = (unsigned short)(((b & 0x80u) << 8) | ((b & 0x7Fu) << 7));
    __half hh = *reinterpret_cast<__half*>(&hb);
    return __half2float(hh) * 256.f;
}
template <bool HI>
__device__ __forceinline__ f32x2 dec2fp8(unsigned w) {
#if HAVE_FP8_DEC
    return __builtin_amdgcn_cvt_pk_f32_fp8((int)w, HI);
#else
    unsigned b0 = HI ? ((w >> 16) & 0xFFu) : (w & 0xFFu);
    unsigned b1 = HI ? (w >> 24) : ((w >> 8) & 0xFFu);
    f32x2 r; r.x = fp8dec1(b0); r.y = fp8dec1(b1); return r;
#endif
}
__device__ __forceinline__ unsigned char f2fp8(float f) {
#if HAVE_FP8_ENC
    return (unsigned char)(__builtin_amdgcn_cvt_pk_fp8_f32(f, f, 0, false) & 0xFF);
#else
    unsigned u = __float_as_uint(f);
    unsigned s = (u >> 24) & 0x80u;
    float a = fabsf(f);
    if (a >= 464.f) return (unsigned char)(s | 0x7E);     // clamp to 448
    if (a < 0.015625f) {                                  // subnormal: q/512
        int q = (int)rintf(a * 512.f);
        return (unsigned char)(s | (unsigned)q);
    }
    int e = (int)((u >> 23) & 0xFF) - 127;
    unsigned man = u & 0x7FFFFFu;
    unsigned keep = man >> 20, rest = man & 0xFFFFFu;
    if (rest > 0x80000u || (rest == 0x80000u && (keep & 1u))) {
        if (++keep == 8u) { keep = 0u; ++e; if (e > 8) return (unsigned char)(s | 0x7E); }
    }
    return (unsigned char)(s | ((unsigned)(e + 7) << 3) | keep);
#endif
}

// ===== setup: weight prep (48 blks) + count_deg (3125 blks) + secbias =======
__global__ __launch_bounds__(256) void setup_kernel(
    const float* __restrict__ W1, const float* __restrict__ Wq,
    const float* __restrict__ Wk, const float* __restrict__ Wv,
    const float* __restrict__ Wo, const float* __restrict__ W2,
    unsigned short* __restrict__ Wt, const int* __restrict__ dst,
    int* __restrict__ deg, const float* __restrict__ sec,
    const float* __restrict__ Wsec, const float* __restrict__ bsec,
    float* __restrict__ secb) {
    const int b = blockIdx.x, t = threadIdx.x;
    if (b < SETUP_W) {
        const int mtx = b >> 3, slice = b & 7;
        const float* W = (mtx == 0) ? W1 : (mtx == 1) ? Wq : (mtx == 2) ? Wk :
                         (mtx == 3) ? Wv : (mtx == 4) ? Wo : W2;
        unsigned short* o = Wt + mtx * 16384;
#pragma unroll
        for (int i = 0; i < 8; ++i) {
            int idx = slice * 2048 + t + 256 * i;   // k-major element index
            int k = idx >> 7, n = idx & 127;
            o[n * 128 + k] = f2bf(W[idx]);
        }
    } else if (b < SETUP_W + SETUP_CNT) {           // count_deg
        int e = (b - SETUP_W) * 256 + t;
        if (e < N_EDGES) atomicAdd(&deg[dst[e]], 1);
    } else {                                        // secbias
        int idx = (b - SETUP_W - SETUP_CNT) * 256 + t;
        if (idx < N_NODES * NHEAD) {
            int n = idx >> 3, h = idx & 7;
            float acc = bsec[h];
#pragma unroll
            for (int j = 0; j < SDIM; ++j)
                acc = fmaf(sec[n * SDIM + j], Wsec[j * NHEAD + h], acc);
            secb[idx] = acc;
        }
    }
}

__global__ __launch_bounds__(256) void blocksum_kernel(const int* __restrict__ deg,
                                                       int* __restrict__ bsum) {
    const int t = threadIdx.x;
    int idx = blockIdx.x * 256 + t;
    int v = (idx < N_NODES) ? deg[idx] : 0;
#pragma unroll
    for (int m = 32; m; m >>= 1) v += __shfl_xor(v, m);
    __shared__ int ws[4];
    if ((t & 63) == 0) ws[t >> 6] = v;
    __syncthreads();
    if (t == 0) bsum[blockIdx.x] = ws[0] + ws[1] + ws[2] + ws[3];
}

__global__ __launch_bounds__(256) void scanfin2_kernel(const int* __restrict__ deg,
                                                       const int* __restrict__ bsum,
                                                       int* __restrict__ rowstart) {
    const int t = threadIdx.x, b = blockIdx.x;
    int v0 = (t < b) ? bsum[t] : 0;
#pragma unroll
    for (int m = 32; m; m >>= 1) v0 += __shfl_xor(v0, m);
    __shared__ int ws[4];
    if ((t & 63) == 0) ws[t >> 6] = v0;
    __syncthreads();
    const int bexc = ws[0] + ws[1] + ws[2] + ws[3];

    int idx = b * 256 + t;
    int v = (idx < N_NODES) ? deg[idx] : 0;
    __shared__ int s[256];
    __syncthreads();
    s[t] = v;
    __syncthreads();
#pragma unroll
    for (int off = 1; off < 256; off <<= 1) {
        int x = (t >= off) ? s[t - off] : 0;
        __syncthreads();
        s[t] += x;
        __syncthreads();
    }
    if (idx < N_NODES) rowstart[idx] = bexc + s[t] - v;
    if (b == 0 && t == 0) rowstart[N_NODES] = N_EDGES;
}

// ===== fused: blocks 0..HQKV_GRID-1 = h+q/k/v GEMM; rest = CSR fill =======
// Round-16 configuration (best measured, 182.0 us): W staged in LDS (Wl) +
// per-wave Ht transpose area, barriers between phases, GEMM blocks first.
// q,v,h stored bf16; k stored fp8 e4m3.
__global__ __launch_bounds__(512) void fill_hqkv_kernel(
    const int* __restrict__ src, const int* __restrict__ dst,
    const int* __restrict__ rowstart, int* __restrict__ ctr,
    int2* __restrict__ epair,
    const float* __restrict__ X, const unsigned short* __restrict__ Wt,
    const float* __restrict__ b1, const float* __restrict__ bq,
    const float* __restrict__ bk, const float* __restrict__ bv,
    unsigned short* __restrict__ hb, unsigned short* __restrict__ qo,
    unsigned char* __restrict__ ko8, unsigned short* __restrict__ vo, int nrows) {
    __shared__ alignas(16) unsigned char Wl[32768];
    __shared__ alignas(16) unsigned char Ht[32768];   // 8 waves x 16 rows x 256B
    const int t = threadIdx.x;

    if (blockIdx.x >= HQKV_GRID) {
        // ---------------- CSR fill ----------------
        int e = (blockIdx.x - HQKV_GRID) * 512 + t;
        if (e < N_EDGES) {
            int d = dst[e];
            int pos = atomicAdd(&ctr[d], 1);
            epair[rowstart[d] + pos] = make_int2(src[e], e);
        }
        return;
    }

    // ---------------- h + q/k/v GEMM ----------------
    const int l = t & 63, wave = t >> 6;
    const int l15 = l & 15, lg = l >> 4;
    const int r0 = blockIdx.x * 128 + wave * 16;
    const int arow = r0 + l15;
    const bool aok = arow < nrows;
    const int orow0 = r0 + lg * 4;
    unsigned char* HtW = Ht + wave * 4096;

    // stage W1
#pragma unroll
    for (int i = 0; i < 4; ++i) {
        int c = t + 512 * i;                 // 2048 16B chunks
        int n = c >> 4, s = c & 15;
        bf16x8 val = *(const bf16x8*)(Wt + c * 8);
        *(bf16x8*)(Wl + n * 256 + ((s * 16) ^ ((n & 7) << 4))) = val;
    }
    // x f32 -> bf16 A-frags
    bf16x8 af[4];
#pragma unroll
    for (int k0 = 0; k0 < 4; ++k0) {
        float4 a0 = {0.f, 0.f, 0.f, 0.f}, a1 = {0.f, 0.f, 0.f, 0.f};
        if (aok) {
            const float4* ap = (const float4*)(X + (size_t)arow * DIM + k0 * 32 + lg * 8);
            a0 = ap[0]; a1 = ap[1];
        }
        bf16x8 f;
        f[0] = (short)f2bf(a0.x); f[1] = (short)f2bf(a0.y);
        f[2] = (short)f2bf(a0.z); f[3] = (short)f2bf(a0.w);
        f[4] = (short)f2bf(a1.x); f[5] = (short)f2bf(a1.y);
        f[6] = (short)f2bf(a1.z); f[7] = (short)f2bf(a1.w);
        af[k0] = f;
    }
    __syncthreads();

    {
        f32x4 acc[8];
#pragma unroll
        for (int n = 0; n < 8; ++n) acc[n] = (f32x4){0.f, 0.f, 0.f, 0.f};
#pragma unroll
        for (int k0 = 0; k0 < 4; ++k0) {
#pragma unroll
            for (int n = 0; n < 8; ++n) {
                int row = n * 16 + l15;
                int kb = (k0 * 64 + lg * 16) ^ ((row & 7) << 4);
                bf16x8 bfr = *(bf16x8*)(Wl + row * 256 + kb);
                acc[n] = __builtin_amdgcn_mfma_f32_16x16x32_bf16(af[k0], bfr, acc[n], 0, 0, 0);
            }
        }
        // epilogue: h = relu(acc + b1) -> hb + per-wave Ht region
#pragma unroll
        for (int n = 0; n < 8; ++n) {
            int col = n * 16 + l15;
            float bvv = b1[col];
#pragma unroll
            for (int i = 0; i < 4; ++i) {
                int rloc = lg * 4 + i;
                unsigned short hv = f2bf(fmaxf(acc[n][i] + bvv, 0.f));
                if (orow0 + i < nrows) hb[(size_t)(orow0 + i) * DIM + col] = hv;
                *(unsigned short*)(HtW + ((rloc * 256 + col * 2) ^ ((rloc & 7) << 4))) = hv;
            }
        }
    }

    // A-frags of h from own wave's Ht region (intra-wave, LDS ops ordered)
    bf16x8 af2[4];
#pragma unroll
    for (int k0 = 0; k0 < 4; ++k0)
        af2[k0] = *(const bf16x8*)(HtW + ((l15 * 256 + k0 * 64 + lg * 16) ^ ((l15 & 7) << 4)));
    __syncthreads();

    for (int m = 0; m < 3; ++m) {
        const unsigned short* wsrc = (m == 0) ? Wt + 16384 : (m == 1) ? Wt + 32768 : Wt + 49152;
        const float* bias = (m == 0) ? bq : (m == 1) ? bk : bv;
#pragma unroll
        for (int i = 0; i < 4; ++i) {
            int c = t + 512 * i;
            int n = c >> 4, s = c & 15;
            bf16x8 val = *(const bf16x8*)(wsrc + c * 8);
            *(bf16x8*)(Wl + n * 256 + ((s * 16) ^ ((n & 7) << 4))) = val;
        }
        __syncthreads();
        f32x4 acc[8];
#pragma unroll
        for (int n = 0; n < 8; ++n) acc[n] = (f32x4){0.f, 0.f, 0.f, 0.f};
#pragma unroll
        for (int k0 = 0; k0 < 4; ++k0) {
#pragma unroll
            for (int n = 0; n < 8; ++n) {
                int row = n * 16 + l15;
                int kb = (k0 * 64 + lg * 16) ^ ((row & 7) << 4);
                bf16x8 bfr = *(bf16x8*)(Wl + row * 256 + kb);
                acc[n] = __builtin_amdgcn_mfma_f32_16x16x32_bf16(af2[k0], bfr, acc[n], 0, 0, 0);
            }
        }
#pragma unroll
        for (int n = 0; n < 8; ++n) {
            int col = n * 16 + l15;
            float bvv = bias[col];
#pragma unroll
            for (int i = 0; i < 4; ++i) {
                int r = orow0 + i;
                if (r < nrows) {
                    float val = acc[n][i] + bvv;
                    if (m == 0)      qo[(size_t)r * DIM + col] = f2bf(val);
                    else if (m == 1) ko8[(size_t)r * DIM + col] = f2fp8(val);
                    else             vo[(size_t)r * DIM + col] = f2bf(val);
                }
            }
        }
        __syncthreads();   // before next restage
    }
}

// fp8 k-row dot against qv[16] floats (row = 16B at kb8 + s*128 + h*16)
__device__ __forceinline__ float score_dot_fp8(const float* qv, uint4 kw) {
    float a0 = 0.f, a1 = 0.f;
    f32x2 p;
    p = dec2fp8<false>(kw.x); a0 = fmaf(qv[0],  p.x, a0); a1 = fmaf(qv[1],  p.y, a1);
    p = dec2fp8<true >(kw.x); a0 = fmaf(qv[2],  p.x, a0); a1 = fmaf(qv[3],  p.y, a1);
    p = dec2fp8<false>(kw.y); a0 = fmaf(qv[4],  p.x, a0); a1 = fmaf(qv[5],  p.y, a1);
    p = dec2fp8<true >(kw.y); a0 = fmaf(qv[6],  p.x, a0); a1 = fmaf(qv[7],  p.y, a1);
    p = dec2fp8<false>(kw.z); a0 = fmaf(qv[8],  p.x, a0); a1 = fmaf(qv[9],  p.y, a1);
    p = dec2fp8<true >(kw.z); a0 = fmaf(qv[10], p.x, a0); a1 = fmaf(qv[11], p.y, a1);
    p = dec2fp8<false>(kw.w); a0 = fmaf(qv[12], p.x, a0); a1 = fmaf(qv[13], p.y, a1);
    p = dec2fp8<true >(kw.w); a0 = fmaf(qv[14], p.x, a0); a1 = fmaf(qv[15], p.y, a1);
    return a0 + a1;
}

// ===== fused scores + softmax + aggregation (wave per dst node) ============
__global__ __launch_bounds__(256) void node_attn_kernel(
    const unsigned short* __restrict__ qb, const unsigned char* __restrict__ kb8,
    const unsigned short* __restrict__ vb, const float* __restrict__ secb,
    const int2* __restrict__ epair, const int* __restrict__ rowstart,
    float* __restrict__ attn_out, unsigned short* __restrict__ aggb) {
    int node = blockIdx.x * 4 + (threadIdx.x >> 6);
    if (node >= N_NODES) return;
    const int lane = threadIdx.x & 63;
    const int start = rowstart[node];
    const int deg = rowstart[node + 1] - start;
    if (deg == 0) {
        ((unsigned*)(aggb + (size_t)node * DIM))[lane] = 0u;
        return;
    }
    const int h = lane & 7;     // head (score phases)
    const int le = lane >> 3;   // edge slot 0..7
    const int hc = le;          // head (aggregation mapping)

    float qv[16];
    {
        const bf16x8* qp = (const bf16x8*)(qb + (size_t)node * DIM + h * DHEAD);
        bf16x8 q0 = qp[0], q1 = qp[1];
#pragma unroll
        for (int i = 0; i < 8; ++i) {
            qv[i] = bf2f((unsigned short)q0[i]);
            qv[8 + i] = bf2f((unsigned short)q1[i]);
        }
    }

    if (deg <= 64) {
        // ---------- fast path: coalesced int2 preload + register scores ----
        int sall = 0, eall = 0;
        if (lane < deg) {
            int2 p = epair[start + lane];
            sall = p.x;
            eall = p.y;
        }
        float sc[8];
        float m = -INFINITY;
#pragma unroll
        for (int t = 0; t < 8; ++t) {
            sc[t] = -INFINITY;
            if (t * 8 < deg) {                       // wave-uniform
                int jj = t * 8 + le;
                bool valid = jj < deg;
                int s = __shfl(sall, valid ? jj : deg - 1);
                uint4 kw = *(const uint4*)(kb8 + (size_t)s * DIM + h * 16);
                float acc = score_dot_fp8(qv, kw);
                if (valid) sc[t] = acc * 0.25f + secb[s * NHEAD + h];
            }
            m = fmaxf(m, sc[t]);
        }
        m = fmaxf(m, __shfl_xor(m, 8));
        m = fmaxf(m, __shfl_xor(m, 16));
        m = fmaxf(m, __shfl_xor(m, 32));

        float ev[8];
        float ssum = 0.f;
#pragma unroll
        for (int t = 0; t < 8; ++t) {
            ev[t] = (t * 8 + le < deg) ? __expf(sc[t] - m) : 0.f;
            ssum += ev[t];
        }
        ssum += __shfl_xor(ssum, 8);
        ssum += __shfl_xor(ssum, 16);
        ssum += __shfl_xor(ssum, 32);
        const float rinv = 1.f / (ssum + 1e-9f);     // head (lane&7)

        float2 acc2 = {0.f, 0.f};
#pragma unroll
        for (int t = 0; t < 8; ++t) {
            if (t * 8 < deg) {                       // wave-uniform
                // batch all 8 gathers (independent, in flight together)
                unsigned vvr[8];
#pragma unroll
                for (int le2 = 0; le2 < 8; ++le2) {
                    int jj = t * 8 + le2;            // uniform
                    int s = __shfl(sall, (jj < deg) ? jj : deg - 1);  // uniform
                    vvr[le2] = ((const unsigned*)(vb + (size_t)s * DIM))[lane];
                }
#pragma unroll
                for (int le2 = 0; le2 < 8; ++le2) {
                    float evd = __shfl(ev[t], le2 * 8 + hc);
                    acc2.x = fmaf(evd, bf2f((unsigned short)(vvr[le2] & 0xFFFFu)), acc2.x);
                    acc2.y = fmaf(evd, bf2f((unsigned short)(vvr[le2] >> 16)), acc2.y);
                }
            }
        }
        const float rinv_c = __shfl(rinv, hc);       // head (lane>>3)
        unsigned short o0 = f2bf(acc2.x * rinv_c);
        unsigned short o1 = f2bf(acc2.y * rinv_c);
        ((unsigned*)(aggb + (size_t)node * DIM))[lane] =
            (unsigned)o0 | ((unsigned)o1 << 16);

        // attn write: shfl hoisted OUT of the divergent guard (EXEC-safe)
#pragma unroll
        for (int t = 0; t < 8; ++t) {
            int jj = t * 8 + le;
            int e = __shfl(eall, (jj < deg) ? jj : 0);   // all lanes execute
            if (jj < deg) attn_out[(size_t)e * NHEAD + h] = ev[t] * rinv;
        }
        return;
    }

    // ---------- slow path (deg > 64): memory-staged, always correct ----------
    float m = -INFINITY;
    for (int j = 0; j < deg; j += 8) {
        int jj = j + le;
        float sc = -INFINITY;
        if (jj < deg) {
            int2 p = epair[start + jj];
            int s = p.x;
            uint4 kw = *(const uint4*)(kb8 + (size_t)s * DIM + h * 16);
            float acc = score_dot_fp8(qv, kw);
            sc = acc * 0.25f + secb[s * NHEAD + h];
            attn_out[(size_t)p.y * NHEAD + h] = sc;
        }
        m = fmaxf(m, sc);
    }
    m = fmaxf(m, __shfl_xor(m, 8));
    m = fmaxf(m, __shfl_xor(m, 16));
    m = fmaxf(m, __shfl_xor(m, 32));

    float ssum = 0.f;
    float2 acc2 = {0.f, 0.f};
    for (int j = 0; j < deg; j += 8) {
        int jj = j + le;
        float ev = 0.f;
        if (jj < deg) {
            int e = epair[start + jj].y;
            ev = __expf(attn_out[(size_t)e * NHEAD + h] - m);
        }
        ssum += ev;
        int lim = deg - j; if (lim > 8) lim = 8;
        for (int le2 = 0; le2 < lim; ++le2) {
            float evd = __shfl(ev, le2 * 8 + hc);
            int s = epair[start + j + le2].x;
            unsigned vv = ((const unsigned*)(vb + (size_t)s * DIM))[lane];
            acc2.x = fmaf(evd, bf2f((unsigned short)(vv & 0xFFFFu)), acc2.x);
            acc2.y = fmaf(evd, bf2f((unsigned short)(vv >> 16)), acc2.y);
        }
    }
    ssum += __shfl_xor(ssum, 8);
    ssum += __shfl_xor(ssum, 16);
    ssum += __shfl_xor(ssum, 32);
    const float rinv = 1.f / (ssum + 1e-9f);
    const float rinv_c = __shfl(rinv, hc);

    unsigned short o0 = f2bf(acc2.x * rinv_c);
    unsigned short o1 = f2bf(acc2.y * rinv_c);
    ((unsigned*)(aggb + (size_t)node * DIM))[lane] =
        (unsigned)o0 | ((unsigned)o1 << 16);

    for (int j = 0; j < deg; j += 8) {
        int jj = j + le;
        if (jj < deg) {
            int e = epair[start + jj].y;
            float sc = attn_out[(size_t)e * NHEAD + h];
            attn_out[(size_t)e * NHEAD + h] = __expf(sc - m) * rinv;
        }
    }
}

// ===== fused double GEMM+LN: out = LN2(mid + relu(mid@W2+b2)),
//       mid = LN1(hb + agg@Wo+bo); round-16 form: Wl+Mt LDS, barriers.
__global__ __launch_bounds__(512) void gemm_ln12_kernel(
    const unsigned short* __restrict__ A,      // aggb
    const unsigned short* __restrict__ Wt,     // Wo @ +0, W2 @ +16384
    const float* __restrict__ bo, const float* __restrict__ b2,
    const unsigned short* __restrict__ resid,  // hb
    const float* __restrict__ g1, const float* __restrict__ be1,
    const float* __restrict__ g2, const float* __restrict__ be2,
    float* __restrict__ outp, int nrows) {
    __shared__ alignas(16) unsigned char Wl[32768];
    __shared__ alignas(16) unsigned char Mt[32768];
    const int t = threadIdx.x;
    const int l = t & 63, wave = t >> 6;
    const int l15 = l & 15, lg = l >> 4;
    const int r0 = blockIdx.x * 128 + wave * 16;
    const int arow = r0 + l15;
    const bool aok = arow < nrows;
    const int orow0 = r0 + lg * 4;
    unsigned char* MtW = Mt + wave * 4096;

    // stage Wo
#pragma unroll
    for (int i = 0; i < 4; ++i) {
        int c = t + 512 * i;
        int n = c >> 4, s = c & 15;
        bf16x8 val = *(const bf16x8*)(Wt + c * 8);
        *(bf16x8*)(Wl + n * 256 + ((s * 16) ^ ((n & 7) << 4))) = val;
    }
    bf16x8 af[4];
#pragma unroll
    for (int k0 = 0; k0 < 4; ++k0) {
        bf16x8 z = (bf16x8){0, 0, 0, 0, 0, 0, 0, 0};
        af[k0] = aok ? *(const bf16x8*)(A + (size_t)arow * DIM + k0 * 32 + lg * 8) : z;
    }
    __syncthreads();

    float mid[8][4];    // bf16-rounded mid values, kept for LN2 residual
    {
        f32x4 acc[8];
#pragma unroll
        for (int n = 0; n < 8; ++n) acc[n] = (f32x4){0.f, 0.f, 0.f, 0.f};
#pragma unroll
        for (int k0 = 0; k0 < 4; ++k0) {
#pragma unroll
            for (int n = 0; n < 8; ++n) {
                int row = n * 16 + l15;
                int kb = (k0 * 64 + lg * 16) ^ ((row & 7) << 4);
                bf16x8 bfr = *(bf16x8*)(Wl + row * 256 + kb);
                acc[n] = __builtin_amdgcn_mfma_f32_16x16x32_bf16(af[k0], bfr, acc[n], 0, 0, 0);
            }
        }
        float bv[8], gv[8], bev[8];
#pragma unroll
        for (int n = 0; n < 8; ++n) {
            int col = n * 16 + l15;
            bv[n] = bo[col]; gv[n] = g1[col]; bev[n] = be1[col];
        }
#pragma unroll
        for (int i = 0; i < 4; ++i) {
            int r = orow0 + i;
            int rloc = lg * 4 + i;
            float xv[8];
            float s = 0.f;
            if (r < nrows) {
#pragma unroll
                for (int n = 0; n < 8; ++n) {
                    float val = acc[n][i] + bv[n]
                              + bf2f(resid[(size_t)r * DIM + n * 16 + l15]);
                    xv[n] = val;
                    s += val;
                }
            } else {
#pragma unroll
                for (int n = 0; n < 8; ++n) xv[n] = 0.f;
            }
            s += __shfl_xor(s, 1); s += __shfl_xor(s, 2);
            s += __shfl_xor(s, 4); s += __shfl_xor(s, 8);
            float mean = s * (1.f / 128.f);
            float var = 0.f;
#pragma unroll
            for (int n = 0; n < 8; ++n) {
                float d = xv[n] - mean;
                var += d * d;
            }
            var += __shfl_xor(var, 1); var += __shfl_xor(var, 2);
            var += __shfl_xor(var, 4); var += __shfl_xor(var, 8);
            float rstd = rsqrtf(var * (1.f / 128.f) + 1e-5f);
#pragma unroll
            for (int n = 0; n < 8; ++n) {
                int col = n * 16 + l15;
                unsigned short mb = f2bf((xv[n] - mean) * rstd * gv[n] + bev[n]);
                mid[n][i] = bf2f(mb);
                *(unsigned short*)(MtW + ((rloc * 256 + col * 2) ^ ((rloc & 7) << 4))) = mb;
            }
        }
    }
    __syncthreads();   // Wo reads + Mt writes complete

    bf16x8 af2[4];
#pragma unroll
    for (int k0 = 0; k0 < 4; ++k0)
        af2[k0] = *(const bf16x8*)(MtW + ((l15 * 256 + k0 * 64 + lg * 16) ^ ((l15 & 7) << 4)));

    // stage W2
#pragma unroll
    for (int i = 0; i < 4; ++i) {
        int c = t + 512 * i;
        int n = c >> 4, s = c & 15;
        bf16x8 val = *(const bf16x8*)(Wt + 16384 + c * 8);
        *(bf16x8*)(Wl + n * 256 + ((s * 16) ^ ((n & 7) << 4))) = val;
    }
    __syncthreads();

    {
        f32x4 acc[8];
#pragma unroll
        for (int n = 0; n < 8; ++n) acc[n] = (f32x4){0.f, 0.f, 0.f, 0.f};
#pragma unroll
        for (int k0 = 0; k0 < 4; ++k0) {
#pragma unroll
            for (int n = 0; n < 8; ++n) {
                int row = n * 16 + l15;
                int kb = (k0 * 64 + lg * 16) ^ ((row & 7) << 4);
                bf16x8 bfr = *(bf16x8*)(Wl + row * 256 + kb);
                acc[n] = __builtin_amdgcn_mfma_f32_16x16x32_bf16(af2[k0], bfr, acc[n], 0, 0, 0);
            }
        }
        float bv[8], gv[8], bev[8];
#pragma unroll
        for (int n = 0; n < 8; ++n) {
            int col = n * 16 + l15;
            bv[n] = b2[col]; gv[n] = g2[col]; bev[n] = be2[col];
        }
#pragma unroll
        for (int i = 0; i < 4; ++i) {
            int r = orow0 + i;
            float xv[8];
            float s = 0.f;
#pragma unroll
            for (int n = 0; n < 8; ++n) {
                float val = fmaxf(acc[n][i] + bv[n], 0.f) + mid[n][i];
                xv[n] = val;
                s += val;
            }
            s += __shfl_xor(s, 1); s += __shfl_xor(s, 2);
            s += __shfl_xor(s, 4); s += __shfl_xor(s, 8);
            float mean = s * (1.f / 128.f);
            float var = 0.f;
#pragma unroll
            for (int n = 0; n < 8; ++n) {
                float d = xv[n] - mean;
                var += d * d;
            }
            var += __shfl_xor(var, 1); var += __shfl_xor(var, 2);
            var += __shfl_xor(var, 4); var += __shfl_xor(var, 8);
            float rstd = rsqrtf(var * (1.f / 128.f) + 1e-5f);
            if (r < nrows) {
#pragma unroll
                for (int n = 0; n < 8; ++n) {
                    int col = n * 16 + l15;
                    outp[(size_t)r * DIM + col] = (xv[n] - mean) * rstd * gv[n] + bev[n];
                }
            }
        }
    }
}

extern "C" void kernel_launch(void* const* d_in, const int* in_sizes, int n_in,
                              void* d_out, int out_size, void* d_ws, size_t ws_size,
                              hipStream_t stream) {
    const float* x    = (const float*)d_in[0];
    const int*   ei   = (const int*)d_in[1];
    const float* sec  = (const float*)d_in[2];
    const float* W1   = (const float*)d_in[3];
    const float* b1   = (const float*)d_in[4];
    const float* W2   = (const float*)d_in[5];
    const float* b2   = (const float*)d_in[6];
    const float* Wq   = (const float*)d_in[7];
    const float* bq   = (const float*)d_in[8];
    const float* Wk   = (const float*)d_in[9];
    const float* bk   = (const float*)d_in[10];
    const float* Wv   = (const float*)d_in[11];
    const float* bvp  = (const float*)d_in[12];
    const float* Wsec = (const float*)d_in[13];
    const float* bsec = (const float*)d_in[14];
    const float* Wo   = (const float*)d_in[15];
    const float* bo   = (const float*)d_in[16];
    const float* g1   = (const float*)d_in[17];
    const float* be1  = (const float*)d_in[18];
    const float* g2   = (const float*)d_in[19];
    const float* be2  = (const float*)d_in[20];

    const int* srcp = ei;             // edge_index[0]
    const int* dstp = ei + N_EDGES;   // edge_index[1]

    char* wsb = (char*)d_ws;
    unsigned short* hb   = (unsigned short*)(wsb);              // 12.8MB bf16
    unsigned short* qbu  = (unsigned short*)(wsb + 12800000);   // bf16
    unsigned char*  kb8  = (unsigned char*)(wsb + 25600000);    // fp8, 6.4MB
    unsigned short* vbu  = (unsigned short*)(wsb + 38400000);   // bf16
    unsigned short* aggb = (unsigned short*)(wsb + 51200000);
    float* secb          = (float*)(wsb + 76800000);            // 1.6MB
    unsigned short* Wt   = (unsigned short*)(wsb + 78400000);   // 192KB
    int* deg             = (int*)(wsb + 78600000);              // 200KB
    int* ctr             = (int*)(wsb + 78800000);              // 200KB
    int* rowstart        = (int*)(wsb + 79000000);              // 200KB+4
    int2* epair          = (int2*)(wsb + 79200256);             // 6.4MB
    int* bsum            = (int*)(wsb + 85600512);              // 784B

    float* outp = (float*)d_out;                 // [N,128]
    float* attn = outp + (size_t)N_NODES * DIM;  // [E,8]

    dim3 blk(256);
    const int wgrid = (N_NODES + 3) / 4;             // 12500

    // zero deg+ctr (adjacent 400KB) — graph-capturable async memset
    hipMemsetAsync(deg, 0, 400000, stream);

    setup_kernel<<<SETUP_W + SETUP_CNT + SETUP_SEC, blk, 0, stream>>>(
        W1, Wq, Wk, Wv, Wo, W2, Wt, dstp, deg, sec, Wsec, bsec, secb);
    blocksum_kernel<<<NSCAN_BLK, blk, 0, stream>>>(deg, bsum);
    scanfin2_kernel<<<NSCAN_BLK, blk, 0, stream>>>(deg, bsum, rowstart);

    fill_hqkv_kernel<<<HQKV_GRID + FILL_GRID, dim3(512), 0, stream>>>(
        srcp, dstp, rowstart, ctr, epair,
        x, Wt, b1, bq, bk, bvp, hb, qbu, kb8, vbu, N_NODES);

    node_attn_kernel<<<wgrid, blk, 0, stream>>>(qbu, kb8, vbu, secb, epair,
                                                rowstart, attn, aggb);

    gemm_ln12_kernel<<<HQKV_GRID, dim3(512), 0, stream>>>(aggb, Wt + 65536, bo, b2, hb,
                                                          g1, be1, g2, be2, outp, N_NODES);
}